// Round 4
// baseline (693.349 us; speedup 1.0000x reference)
//
#include <hip/hip_runtime.h>

typedef unsigned short u16;
typedef unsigned long long u64;
typedef _Float16 h16;
typedef __attribute__((ext_vector_type(8))) _Float16 h16x8;
typedef __attribute__((ext_vector_type(4))) _Float16 h16x4;
typedef __attribute__((ext_vector_type(4))) float f32x4;

__device__ __forceinline__ float b2f(u16 u) {
  unsigned x = ((unsigned)u) << 16;
  return __uint_as_float(x);
}
__device__ __forceinline__ unsigned fkey(float f) {
  unsigned b = __float_as_uint(f);
  return (b & 0x80000000u) ? ~b : (b | 0x80000000u);
}
__device__ __forceinline__ float unfkey(unsigned u) {
  unsigned b = (u & 0x80000000u) ? (u ^ 0x80000000u) : ~u;
  return __uint_as_float(b);
}
__device__ __forceinline__ f32x4 mfma16(h16x8 a, h16x8 b, f32x4 c) {
  return __builtin_amdgcn_mfma_f32_16x16x32_f16(a, b, c, 0, 0, 0);
}
__device__ __forceinline__ void gl_lds16(const void* g, void* l) {
  __builtin_amdgcn_global_load_lds(
      (const __attribute__((address_space(1))) unsigned*)g,
      (__attribute__((address_space(3))) unsigned*)l, 16, 0, 0);
}
__device__ __forceinline__ u64 wave_max_u64(u64 k) {
#pragma unroll
  for (int off = 32; off; off >>= 1) {
    u64 o = __shfl_xor(k, off);
    if (o > k) k = o;
  }
  return k;
}
__device__ __forceinline__ float cvt_in(const void* p, int i, int f) {
  return f ? ((const float*)p)[i] : b2f(((const u16*)p)[i]);
}

// per-block dtype detection from X's first 8192 u16 slots (same sample set
// as the old detect_dtype kernel); returns 1 if inputs are f32 (expected)
__device__ __forceinline__ int detect_f32_local(const u16* __restrict__ X) {
  __shared__ int dcnt;
  if (threadIdx.x == 0) dcnt = 0;
  __syncthreads();
  int sane = 0;
  for (int j = threadIdx.x; j < 4096; j += blockDim.x) {
    u16 u = X[j * 2];
    int e = (u >> 7) & 0xff;
    if (u == 0 || (e >= 112 && e <= 142)) sane++;
  }
  atomicAdd(&dcnt, sane);
  __syncthreads();
  return (dcnt < 3072) ? 1 : 0;
}

// split X to hi/lo fp16 + f32 copy (local dtype detect)
__global__ __launch_bounds__(256) void split_input3(
    const void* __restrict__ in, h16* __restrict__ hi, h16* __restrict__ lo,
    float* __restrict__ f32out, int n) {
  int f = detect_f32_local((const u16*)in);
  int stride = gridDim.x * 256;
  for (int i = blockIdx.x * 256 + threadIdx.x; i < n; i += stride) {
    float x = cvt_in(in, i, f);
    h16 h = (h16)x;
    hi[i] = h;
    lo[i] = (h16)(x - (float)h);
    if (f32out) f32out[i] = x;
  }
}

// split L (blocks 0..255) and W (blocks 256..319); local detect from X
__global__ __launch_bounds__(256) void split_LW(
    const void* __restrict__ Xin, const void* __restrict__ Lin,
    h16* __restrict__ Lhi, h16* __restrict__ Llo, const void* __restrict__ Win,
    h16* __restrict__ Whi, h16* __restrict__ Wlo) {
  int f = detect_f32_local((const u16*)Xin);
  int tid = threadIdx.x;
  if (blockIdx.x < 256) {
#pragma unroll
    for (int j = 0; j < 4; ++j) {
      int i = blockIdx.x * 1024 + j * 256 + tid;
      float x = cvt_in(Lin, i, f);
      h16 h = (h16)x;
      Lhi[i] = h;
      Llo[i] = (h16)(x - (float)h);
    }
  } else {
    int b = blockIdx.x - 256;
#pragma unroll
    for (int j = 0; j < 4; ++j) {
      int i = b * 1024 + j * 256 + tid;
      float x = cvt_in(Win, i, f);
      h16 h = (h16)x;
      Whi[i] = h;
      Wlo[i] = (h16)(x - (float)h);
    }
  }
}

// theta+bias conv + scalars (local detect from X)
__global__ __launch_bounds__(1024) void prep_small(
    const void* __restrict__ Xin, const void* __restrict__ theta,
    const void* __restrict__ bpin, const void* __restrict__ alpha,
    const void* __restrict__ rho_raw, float* __restrict__ thetaf,
    float* __restrict__ biasf, float* __restrict__ scal) {
  int f = detect_f32_local((const u16*)Xin);
  int tid = threadIdx.x;
  if (tid < 768)
    thetaf[tid] = cvt_in(theta, tid, f);
  else if (tid < 1024)
    biasf[tid - 768] = cvt_in(bpin, tid - 768, f);
  if (tid == 0) {
    float a[4], e[4], m = -1e30f, s = 0.f;
    for (int i = 0; i < 4; ++i) {
      a[i] = cvt_in(alpha, i, f);
      m = fmaxf(m, a[i]);
    }
    for (int i = 0; i < 4; ++i) { e[i] = expf(a[i] - m); s += e[i]; }
    for (int i = 0; i < 4; ++i) scal[i] = e[i] / s;
    float rr = cvt_in(rho_raw, 0, f);
    scal[4] = 1.f / (1.f + expf(-rr));
  }
}

// ---------------------------------------------------------------------------
// Split-precision NT GEMM (64x64 tile): alpha*(Ah Bh^T + Ah Bl^T + Al Bh^T)
// SPLITOUT=1: write hi/lo fp16 planes (Y path); else f32 C (+bias).
// ---------------------------------------------------------------------------
template <bool BIAS, bool SPLITOUT>
__global__ __launch_bounds__(256) void gemm3_nt(
    const h16* __restrict__ Ah, const h16* __restrict__ Al,
    const h16* __restrict__ Bh, const h16* __restrict__ Bl,
    float* __restrict__ C, h16* __restrict__ Yh, h16* __restrict__ Yl,
    const float* __restrict__ bias, float alpha, int M, int Nc, int Kd,
    long batchA, long batchB, long batchC) {
  const h16* Abh = Ah + (size_t)blockIdx.z * batchA;
  const h16* Abl = Al + (size_t)blockIdx.z * batchA;
  const h16* Bbh = Bh + (size_t)blockIdx.z * batchB;
  const h16* Bbl = Bl + (size_t)blockIdx.z * batchB;
  int bn = blockIdx.x, bm = blockIdx.y;
  int tid = threadIdx.x;
  int wid = tid >> 6, lane = tid & 63;
  __shared__ h16 Ash[64 * 40], Asl[64 * 40], Bsh[64 * 40], Bsl[64 * 40];
  f32x4 acc00 = {}, acc01 = {}, acc10 = {}, acc11 = {};
  int lr = tid >> 2;
  int lc = (tid & 3) << 3;
  size_t aoff = (size_t)(bm * 64 + lr) * Kd + lc;
  size_t boff = (size_t)(bn * 64 + lr) * Kd + lc;
  int wm = (wid & 1) * 32, wn = (wid >> 1) * 32;
  int fr = lane & 15;
  int fc = (lane >> 4) << 3;
  for (int k0 = 0; k0 < Kd; k0 += 32) {
    uint4 avh = *(const uint4*)(Abh + aoff + k0);
    uint4 avl = *(const uint4*)(Abl + aoff + k0);
    uint4 bvh = *(const uint4*)(Bbh + boff + k0);
    uint4 bvl = *(const uint4*)(Bbl + boff + k0);
    __syncthreads();
    *(uint4*)(Ash + lr * 40 + lc) = avh;
    *(uint4*)(Asl + lr * 40 + lc) = avl;
    *(uint4*)(Bsh + lr * 40 + lc) = bvh;
    *(uint4*)(Bsl + lr * 40 + lc) = bvl;
    __syncthreads();
    h16x8 a0h = *(const h16x8*)(Ash + (wm + fr) * 40 + fc);
    h16x8 a1h = *(const h16x8*)(Ash + (wm + 16 + fr) * 40 + fc);
    h16x8 b0h = *(const h16x8*)(Bsh + (wn + fr) * 40 + fc);
    h16x8 b1h = *(const h16x8*)(Bsh + (wn + 16 + fr) * 40 + fc);
    h16x8 a0l = *(const h16x8*)(Asl + (wm + fr) * 40 + fc);
    h16x8 a1l = *(const h16x8*)(Asl + (wm + 16 + fr) * 40 + fc);
    h16x8 b0l = *(const h16x8*)(Bsl + (wn + fr) * 40 + fc);
    h16x8 b1l = *(const h16x8*)(Bsl + (wn + 16 + fr) * 40 + fc);
    acc00 = mfma16(a0h, b0h, acc00);
    acc01 = mfma16(a0h, b1h, acc01);
    acc10 = mfma16(a1h, b0h, acc10);
    acc11 = mfma16(a1h, b1h, acc11);
    acc00 = mfma16(a0h, b0l, acc00);
    acc01 = mfma16(a0h, b1l, acc01);
    acc10 = mfma16(a1h, b0l, acc10);
    acc11 = mfma16(a1h, b1l, acc11);
    acc00 = mfma16(a0l, b0h, acc00);
    acc01 = mfma16(a0l, b1h, acc01);
    acc10 = mfma16(a1l, b0h, acc10);
    acc11 = mfma16(a1l, b1h, acc11);
  }
  int crow = (lane >> 4) << 2;
  int ccol = lane & 15;
  f32x4 accs[2][2] = {{acc00, acc01}, {acc10, acc11}};
#pragma unroll
  for (int i = 0; i < 2; ++i)
#pragma unroll
    for (int j = 0; j < 2; ++j) {
      int r0 = bm * 64 + wm + 16 * i + crow;
      int c0 = bn * 64 + wn + 16 * j + ccol;
#pragma unroll
      for (int rg = 0; rg < 4; ++rg) {
        size_t off = (size_t)(r0 + rg) * Nc + c0;
        float v = accs[i][j][rg] * alpha;
        if constexpr (SPLITOUT) {
          h16* Yhb = Yh + (size_t)blockIdx.z * batchC;
          h16* Ylb = Yl + (size_t)blockIdx.z * batchC;
          h16 hh = (h16)v;
          Yhb[off] = hh;
          Ylb[off] = (h16)(v - (float)hh);
        } else {
          if constexpr (BIAS) v += bias[c0];
          float* Cb = C + (size_t)blockIdx.z * batchC;
          Cb[off] = v;
        }
      }
    }
}

// ---------------------------------------------------------------------------
// Split-precision NT GEMM, 128x128 tile, global_load_lds staging, XOR swizzle.
// ---------------------------------------------------------------------------
__global__ __launch_bounds__(256) void gemm3_big(
    const h16* __restrict__ Ah, const h16* __restrict__ Al,
    const h16* __restrict__ Bh, const h16* __restrict__ Bl,
    float* __restrict__ C, float alpha, int M, int Nc, int Kd) {
  __shared__ h16 sAh[128 * 32], sAl[128 * 32], sBh[128 * 32], sBl[128 * 32];
  int tid = threadIdx.x, wid = tid >> 6, lane = tid & 63;
  int bm = blockIdx.y, bn = blockIdx.x;
  int srow = 32 * wid + (lane >> 2);
  int scnk = lane & 3;
  int fr = lane & 15, fcc = lane >> 4;
  f32x4 acc[4][4] = {};
  const h16* gA[2] = {Ah, Al};
  const h16* gB[2] = {Bh, Bl};
  h16* sA[2] = {sAh, sAl};
  h16* sB[2] = {sBh, sBl};
  int wm = (wid & 1) * 64, wn = (wid >> 1) * 64;
  for (int k0 = 0; k0 < Kd; k0 += 32) {
    __syncthreads();
#pragma unroll
    for (int h = 0; h < 2; ++h) {
      int r = srow + 16 * h;
      int cs = scnk ^ ((r >> 1) & 3);
      size_t goffA = (size_t)(bm * 128 + r) * Kd + k0 + cs * 8;
      size_t goffB = (size_t)(bn * 128 + r) * Kd + k0 + cs * 8;
      int loff = (32 * wid + 16 * h) * 32;
#pragma unroll
      for (int p = 0; p < 2; ++p) {
        gl_lds16(gA[p] + goffA, sA[p] + loff);
        gl_lds16(gB[p] + goffB, sB[p] + loff);
      }
    }
    __syncthreads();
    h16x8 fa[2][4], fb[2][4];
#pragma unroll
    for (int i = 0; i < 4; ++i) {
      int ra = wm + 16 * i + fr;
      int ca = (fcc ^ ((ra >> 1) & 3)) * 8;
      fa[0][i] = *(const h16x8*)(sAh + ra * 32 + ca);
      fa[1][i] = *(const h16x8*)(sAl + ra * 32 + ca);
      int rb = wn + 16 * i + fr;
      int cb = (fcc ^ ((rb >> 1) & 3)) * 8;
      fb[0][i] = *(const h16x8*)(sBh + rb * 32 + cb);
      fb[1][i] = *(const h16x8*)(sBl + rb * 32 + cb);
    }
#pragma unroll
    for (int i = 0; i < 4; ++i)
#pragma unroll
      for (int j = 0; j < 4; ++j) {
        acc[i][j] = mfma16(fa[0][i], fb[0][j], acc[i][j]);
        acc[i][j] = mfma16(fa[0][i], fb[1][j], acc[i][j]);
        acc[i][j] = mfma16(fa[1][i], fb[0][j], acc[i][j]);
      }
  }
  int crow = (lane >> 4) << 2, ccol = lane & 15;
#pragma unroll
  for (int i = 0; i < 4; ++i)
#pragma unroll
    for (int j = 0; j < 4; ++j) {
      int r0 = bm * 128 + wm + 16 * i + crow;
      int c0 = bn * 128 + wn + 16 * j + ccol;
#pragma unroll
      for (int rg = 0; rg < 4; ++rg)
        C[(size_t)(r0 + rg) * Nc + c0] = acc[i][j][rg] * alpha;
    }
}

// ---------------------------------------------------------------------------
// fp16 NT GEMM for all 4 heads' E@X.
// v4: same 64x256 tile / 40 KB dbuf LDS / syncthreads-only schedule as v3,
// but 512 threads (8 waves, 2Mx4N decomposition, acc[2][4] per wave).
// 1024 blocks = 4/CU by LDS; 8 waves/block -> 32 waves/CU (8/SIMD) for
// latency hiding (v3 measured: latency-bound at 4 waves/SIMD, Occ 32%).
// __launch_bounds__(512, 8) pins VGPR <= 64 so the wave cap holds.
// ---------------------------------------------------------------------------
__global__ __launch_bounds__(512, 8) void gemm_ks4(
    const h16* __restrict__ Eall, const h16* __restrict__ B,
    float* __restrict__ Cpart) {
  __shared__ h16 sA[2][64 * 32];    // 8 KB
  __shared__ h16 sB[2][256 * 32];   // 32 KB
  int tid = threadIdx.x, wid = tid >> 6, lane = tid & 63;
  int bm = blockIdx.x, zz = blockIdx.y;  // grid (64, 16)
  int head = zz >> 2, kz = zz & 3;
  const h16* A =
      Eall + (size_t)head * 4096 * 4096 + (size_t)(bm * 64) * 4096 + kz * 1024;
  const h16* Bb = B + kz * 1024;
  int r16 = lane >> 2;   // 0..15 (row within a 16-row staging slab)
  int scnk = lane & 3;   // 16B chunk within 32-col row
  int fr = lane & 15, fcc = lane >> 4;
  int wr = wid >> 2;     // 0..1 -> M offset wr*32
  int wc = wid & 3;      // 0..3 -> N offset wc*64
  f32x4 acc[2][4] = {};

  // stage one 64x32 A slab + 256x32 B slab into buffer `buf`
  // (each wave: 2 B slabs of 16 rows; waves 0..3 also 1 A slab)
  auto stage = [&](int buf, int k0) {
#pragma unroll
    for (int p = 0; p < 2; ++p) {
      int r = wid * 32 + p * 16 + r16;
      int cs = scnk ^ ((r >> 1) & 3);
      gl_lds16(Bb + (size_t)r * 4096 + k0 + cs * 8,
               &sB[buf][(wid * 32 + p * 16) * 32]);
    }
    if (wid < 4) {
      int r = wid * 16 + r16;
      int cs = scnk ^ ((r >> 1) & 3);
      gl_lds16(A + (size_t)r * 4096 + k0 + cs * 8, &sA[buf][(wid * 16) * 32]);
    }
  };
  auto compute = [&](int buf) {
    h16x8 fa[2], fb[4];
#pragma unroll
    for (int i = 0; i < 2; ++i) {
      int ra = wr * 32 + 16 * i + fr;
      int ca = (fcc ^ ((ra >> 1) & 3)) * 8;
      fa[i] = *(const h16x8*)(&sA[buf][ra * 32 + ca]);
    }
#pragma unroll
    for (int j = 0; j < 4; ++j) {
      int rb = wc * 64 + 16 * j + fr;
      int cb = (fcc ^ ((rb >> 1) & 3)) * 8;
      fb[j] = *(const h16x8*)(&sB[buf][rb * 32 + cb]);
    }
#pragma unroll
    for (int i = 0; i < 2; ++i)
#pragma unroll
      for (int j = 0; j < 4; ++j)
        acc[i][j] = mfma16(fa[i], fb[j], acc[i][j]);
  };

  stage(0, 0);       // prologue: fill buf 0
  __syncthreads();   // full drain: buf 0 ready
  for (int t = 0; t < 31; ++t) {
    int cur = t & 1;
    stage(cur ^ 1, (t + 1) * 32);  // issue next tile's loads (fly under MFMA)
    compute(cur);
    __syncthreads();  // drain: next buf ready; cur free for overwrite
  }
  compute(1);  // t = 31 (buf 1 drained by last syncthreads)

  float* Cp = Cpart + (size_t)zz * 4096 * 256;
  int crow = (lane >> 4) << 2, ccol = lane & 15;
#pragma unroll
  for (int i = 0; i < 2; ++i)
#pragma unroll
    for (int j = 0; j < 4; ++j) {
      int r0 = bm * 64 + wr * 32 + 16 * i + crow;
      int c0 = wc * 64 + 16 * j + ccol;
#pragma unroll
      for (int rg = 0; rg < 4; ++rg)
        Cp[(size_t)(r0 + rg) * 256 + c0] = acc[i][j][rg];
    }
}

// merged: blocks 0..1023 = ks_reduce4 (Zk); blocks 1024..1087 = hist_part
__global__ __launch_bounds__(256) void ksred_hist(
    const float* __restrict__ Cpart, const float* __restrict__ scal,
    const float* __restrict__ rowSinv, float* __restrict__ Zk,
    const float* __restrict__ topv, const int* __restrict__ topi,
    int* __restrict__ pCnt, float* __restrict__ pDv,
    float* __restrict__ DeIS) {
  __shared__ int lc[4096];
  __shared__ float ld[4096];
  int tid = threadIdx.x;
  if (blockIdx.x < 1024) {
    int i = (blockIdx.x * 256 + tid) * 4;
    int row = i >> 8;
    float4 out = {0.f, 0.f, 0.f, 0.f};
#pragma unroll
    for (int k = 0; k < 4; ++k) {
      float4 s = {0.f, 0.f, 0.f, 0.f};
#pragma unroll
      for (int z = 0; z < 4; ++z) {
        float4 p =
            *(const float4*)(Cpart + (size_t)(k * 4 + z) * 4096 * 256 + i);
        s.x += p.x; s.y += p.y; s.z += p.z; s.w += p.w;
      }
      float sc = scal[k] * rowSinv[k * 4096 + row];
      out.x += sc * s.x; out.y += sc * s.y;
      out.z += sc * s.z; out.w += sc * s.w;
    }
    *(float4*)(Zk + i) = out;
  } else {
    int b = blockIdx.x - 1024;  // 0..63
    for (int j = tid; j < 4096; j += 256) { lc[j] = 0; ld[j] = 0.f; }
    __syncthreads();
    int base = b * 4096;
#pragma unroll
    for (int j = 0; j < 16; ++j) {
      int t = base + j * 256 + tid;
      atomicAdd(&lc[topi[t]], 1);
      atomicAdd(&ld[topi[t]], topv[t]);
    }
    __syncthreads();
    for (int j = tid; j < 4096; j += 256) {
      pCnt[base + j] = lc[j];
      pDv[base + j] = ld[j];
    }
    int e = b * 256 + tid;
    const float4* p = (const float4*)(topv + ((size_t)e << 4));
    float4 a = p[0], bb = p[1], c = p[2], d = p[3];
    float s = ((a.x + a.y) + (a.z + a.w)) + ((bb.x + bb.y) + (bb.z + bb.w)) +
              ((c.x + c.y) + (c.z + c.w)) + ((d.x + d.y) + (d.z + d.w));
    DeIS[e] = 1.0f / sqrtf(s + 1e-9f);
  }
}

// 16-bit transpose
__global__ __launch_bounds__(256) void transpose16(
    const u16* __restrict__ in, u16* __restrict__ out, int rows, int cols) {
  __shared__ u16 t[32][33];
  const u16* ib = in + (size_t)blockIdx.z * rows * cols;
  u16* ob = out + (size_t)blockIdx.z * rows * cols;
  int r0 = blockIdx.x * 32, c0 = blockIdx.y * 32;
  int tx = threadIdx.x & 31, ty = threadIdx.x >> 5;
#pragma unroll
  for (int i = 0; i < 32; i += 8)
    t[ty + i][tx] = ib[(size_t)(r0 + ty + i) * cols + c0 + tx];
  __syncthreads();
#pragma unroll
  for (int i = 0; i < 32; i += 8)
    ob[(size_t)(c0 + ty + i) * rows + r0 + tx] = t[tx][ty + i];
}

// ---------------------------------------------------------------------------
// fused per-row (one wave per row): max -> threshold T -> exp/E-write +
// candidate push -> exact jax-tiebreak top-16 from candidates
// ---------------------------------------------------------------------------
__global__ __launch_bounds__(256) void row_softmax_topk(
    const float* __restrict__ A, float* __restrict__ topv,
    int* __restrict__ topi, h16* __restrict__ E, float* __restrict__ rowSinvK,
    int khead) {
  __shared__ u64 candK[4][256];
  __shared__ int candN[4];
  int wid = threadIdx.x >> 6, lane = threadIdx.x & 63;
  int row = blockIdx.x * 4 + wid;
  const float* arow = A + ((size_t)row << 12);
  if (lane == 0) candN[wid] = 0;
  __syncthreads();
  float lm = -INFINITY;
#pragma unroll
  for (int t = 0; t < 16; ++t) {
    float4 v = *(const float4*)(arow + (t << 8) + (lane << 2));
    lm = fmaxf(lm, fmaxf(fmaxf(v.x, v.y), fmaxf(v.z, v.w)));
  }
  float m = lm;
#pragma unroll
  for (int off = 32; off; off >>= 1) m = fmaxf(m, __shfl_xor(m, off));
  u64 lk = ((u64)fkey(lm) << 32) | (unsigned)lane;
  float T = 0.f;
  for (int r = 0; r < 16; ++r) {
    u64 k2 = wave_max_u64(lk);
    if (lk == k2) lk = 0;
    if (r == 15) T = unfkey((unsigned)(k2 >> 32));
  }
  h16* erow = E + ((size_t)row << 12);
  int* cn = &candN[wid];
  u64* ck = candK[wid];
  float s = 0.f;
  for (int t = 0; t < 16; ++t) {
    int c = (t << 8) + (lane << 2);
    float4 v = *(const float4*)(arow + c);
    float e0 = __expf(v.x - m), e1 = __expf(v.y - m);
    float e2 = __expf(v.z - m), e3 = __expf(v.w - m);
    s += (e0 + e1) + (e2 + e3);
    h16x4 hv = {(h16)e0, (h16)e1, (h16)e2, (h16)e3};
    *(h16x4*)(erow + c) = hv;
    if (v.x >= T) {
      int sl = atomicAdd(cn, 1);
      if (sl < 256) ck[sl] = ((u64)fkey(v.x) << 32) | (unsigned)(~(unsigned)c);
    }
    if (v.y >= T) {
      int sl = atomicAdd(cn, 1);
      if (sl < 256) ck[sl] = ((u64)fkey(v.y) << 32) | (unsigned)(~(unsigned)(c + 1));
    }
    if (v.z >= T) {
      int sl = atomicAdd(cn, 1);
      if (sl < 256) ck[sl] = ((u64)fkey(v.z) << 32) | (unsigned)(~(unsigned)(c + 2));
    }
    if (v.w >= T) {
      int sl = atomicAdd(cn, 1);
      if (sl < 256) ck[sl] = ((u64)fkey(v.w) << 32) | (unsigned)(~(unsigned)(c + 3));
    }
  }
#pragma unroll
  for (int off = 32; off; off >>= 1) s += __shfl_xor(s, off);
  if (lane == 0) rowSinvK[row] = 1.f / s;
  __syncthreads();
  int cnt = min(*cn, 256);
  u64 loc[4] = {0ull, 0ull, 0ull, 0ull};
  int nl = 0;
  for (int j = lane; j < cnt; j += 64)
    if (nl < 4) loc[nl++] = ck[j];
#define CSW(a, b)                     \
  {                                   \
    if (loc[b] > loc[a]) {            \
      u64 tt = loc[a];                \
      loc[a] = loc[b];                \
      loc[b] = tt;                    \
    }                                 \
  }
  CSW(0, 1) CSW(2, 3) CSW(0, 2) CSW(1, 3) CSW(1, 2)
#undef CSW
  float myv = 0.f;
  int myi = 0;
  float sum16 = 0.f;
  for (int r = 0; r < 16; ++r) {
    u64 key = loc[0];
    u64 k2 = wave_max_u64(key);
    float wv = unfkey((unsigned)(k2 >> 32));
    int wi = (int)(~(unsigned)(k2 & 0xffffffffu));
    if (key == k2 && key != 0ull) {
      loc[0] = loc[1];
      loc[1] = loc[2];
      loc[2] = loc[3];
      loc[3] = 0ull;
    }
    sum16 += expf(wv - m);
    if (r == lane) { myv = wv; myi = wi; }
  }
  if (lane < 16) {
    size_t o = (((size_t)khead << 12) + row) * 16 + lane;
    topv[o] = expf(myv - m) / (sum16 + 1e-9f * s);
    topi[o] = myi;
  }
}

// per-bin reduce over 64 blocks: cnt, Dvis, block prefix; + fused v0 init
__global__ __launch_bounds__(256) void col_scan(
    const int* __restrict__ pCnt, const float* __restrict__ pDv,
    int* __restrict__ cnt, float* __restrict__ Dvis,
    int* __restrict__ blockBase, float* __restrict__ v0) {
  int i = blockIdx.x * 256 + threadIdx.x;  // grid 16 -> 4096
  int run = 0;
  float dv = 0.f;
#pragma unroll
  for (int b = 0; b < 64; ++b) {
    blockBase[b * 4096 + i] = run;
    run += pCnt[b * 4096 + i];
    dv += pDv[b * 4096 + i];
  }
  cnt[i] = run;
  Dvis[i] = sqrtf(1.0f / (dv + 1e-9f));
  {
    int tid = i;
    unsigned j = (unsigned)(tid & 2047);
    unsigned x0 = j, x1 = j + 2048u;
    const unsigned ks0 = 0u, ks1 = 1u, ks2 = 0x1BD11BDAu;
#define TF_R(r)                                \
    {                                          \
      x0 += x1;                                \
      x1 = (x1 << (r)) | (x1 >> (32 - (r)));   \
      x1 ^= x0;                                \
    }
    x0 += ks0; x1 += ks1;
    TF_R(13) TF_R(15) TF_R(26) TF_R(6)  x0 += ks1; x1 += ks2 + 1u;
    TF_R(17) TF_R(29) TF_R(16) TF_R(24) x0 += ks2; x1 += ks0 + 2u;
    TF_R(13) TF_R(15) TF_R(26) TF_R(6)  x0 += ks0; x1 += ks1 + 3u;
    TF_R(17) TF_R(29) TF_R(16) TF_R(24) x0 += ks1; x1 += ks2 + 4u;
    TF_R(13) TF_R(15) TF_R(26) TF_R(6)  x0 += ks2; x1 += ks0 + 5u;
#undef TF_R
    unsigned bits = (tid < 2048) ? x0 : x1;
    float u01 = __uint_as_float((bits >> 9) | 0x3f800000u) - 1.0f;
    const float lo = -0.99999994f;
    float u = fmaxf(lo, u01 * 2.0f + lo);
    float w = -log1pf(-u * u);
    float p;
    if (w < 5.0f) {
      float t = w - 2.5f;
      p = 2.81022636e-08f;
      p = 3.43273939e-07f + p * t;
      p = -3.5233877e-06f + p * t;
      p = -4.39150654e-06f + p * t;
      p = 0.00021858087f + p * t;
      p = -0.00125372503f + p * t;
      p = -0.00417768164f + p * t;
      p = 0.246640727f + p * t;
      p = 1.50140941f + p * t;
    } else {
      float t = sqrtf(w) - 3.0f;
      p = -0.000200214257f;
      p = 0.000100950558f + p * t;
      p = 0.00134934322f + p * t;
      p = -0.00367342844f + p * t;
      p = 0.00573950773f + p * t;
      p = -0.0076224613f + p * t;
      p = 0.00943887047f + p * t;
      p = 1.00167406f + p * t;
      p = 2.83297682f + p * t;
    }
    v0[tid] = 1.41421354f * (p * u);
  }
}

// exclusive scan of cnt[4096] -> rowptr[4097]
__global__ __launch_bounds__(256) void scan_rowptr(const int* __restrict__ cnt,
                                                   int* __restrict__ rowptr) {
  __shared__ int part[256];
  int tid = threadIdx.x;
  int base = tid * 16;
  int loc[16];
  int s = 0;
#pragma unroll
  for (int j = 0; j < 16; ++j) { loc[j] = s; s += cnt[base + j]; }
  part[tid] = s;
  __syncthreads();
  for (int off = 1; off < 256; off <<= 1) {
    int v = (tid >= off) ? part[tid - off] : 0;
    __syncthreads();
    part[tid] += v;
    __syncthreads();
  }
  int pre = (tid == 0) ? 0 : part[tid - 1];
#pragma unroll
  for (int j = 0; j < 16; ++j) rowptr[base + j] = pre + loc[j];
  if (tid == 255) rowptr[4096] = part[255];
}

// fill cvals + CSR transpose via LDS cursors (no global atomics)
__global__ __launch_bounds__(256) void csr_fill3(
    const float* __restrict__ topv, const int* __restrict__ topi,
    const float* __restrict__ Dvis, const float* __restrict__ DeIS,
    const int* __restrict__ rowptr, const int* __restrict__ blockBase,
    float* __restrict__ cvals, int* __restrict__ colE,
    float* __restrict__ cvalR) {
  __shared__ int lcur[4096];
  int tid = threadIdx.x, b = blockIdx.x;  // grid 64
  int base = b * 4096;
  for (int j = tid; j < 4096; j += 256)
    lcur[j] = rowptr[j] + blockBase[base + j];
  __syncthreads();
#pragma unroll
  for (int j = 0; j < 16; ++j) {
    int t = base + j * 256 + tid;
    int i = topi[t];
    int e = t >> 4;
    float c = Dvis[i] * topv[t] * DeIS[e];
    cvals[t] = c;
    int slot = atomicAdd(&lcur[i], 1);
    colE[slot] = e;
    cvalR[slot] = c;
  }
}

// g[e] = sum_p c[e,p] * v[idx[e,p]]
__global__ __launch_bounds__(256) void spmv_edge(
    const float* __restrict__ cvals, const int* __restrict__ topi,
    const float* __restrict__ v, float* __restrict__ g) {
  int e = blockIdx.x * 256 + threadIdx.x;  // grid 64
  float acc = 0.f;
#pragma unroll
  for (int p = 0; p < 16; ++p)
    acc += cvals[e * 16 + p] * v[topi[e * 16 + p]];
  g[e] = acc;
}

// vout[i] = vin[i] - sum_{j in row i} cvalR[j]*g[colE[j]]
__global__ __launch_bounds__(256) void spmv_row(
    const int* __restrict__ rowptr, const int* __restrict__ colE,
    const float* __restrict__ cvalR, const float* __restrict__ g,
    const float* __restrict__ vin, float* __restrict__ vout) {
  int wid = threadIdx.x >> 6, lane = threadIdx.x & 63;
  int row = blockIdx.x * 4 + wid;  // grid 1024
  int s = rowptr[row], e = rowptr[row + 1];
  float acc = 0.f;
  for (int j = s + lane; j < e; j += 64) acc += cvalR[j] * g[colE[j]];
#pragma unroll
  for (int off = 32; off; off >>= 1) acc += __shfl_xor(acc, off);
  if (lane == 0) vout[row] = vin[row] - acc;
}

// lam = clip((w5.w6)/(w5.w5), 1e-3) -> scal[5]
__global__ __launch_bounds__(256) void pi_dots(const float* __restrict__ w5,
                                               const float* __restrict__ w6,
                                               float* __restrict__ scal) {
  __shared__ float r1[256], r2[256];
  int tid = threadIdx.x;
  float a = 0.f, b = 0.f;
  for (int i = tid; i < 4096; i += 256) {
    float x = w5[i];
    a += x * x;
    b += x * w6[i];
  }
  r1[tid] = a; r2[tid] = b;
  __syncthreads();
  for (int off = 128; off; off >>= 1) {
    if (tid < off) { r1[tid] += r1[tid + off]; r2[tid] += r2[tid + off]; }
    __syncthreads();
  }
  if (tid == 0) scal[5] = fmaxf(r2[0] / r1[0], 1e-3f);
}

// G[e,:] = sum_p c[e,p] * M[idx[e,p],:]  — MLP-unrolled
__global__ __launch_bounds__(256) void spmm_edge(
    const float* __restrict__ cvals, const int* __restrict__ topi,
    const float* __restrict__ M, float* __restrict__ G) {
  int wid = threadIdx.x >> 6, lane = threadIdx.x & 63;
  int e = blockIdx.x * 4 + wid;  // grid 4096
  int cb = lane << 2;
  const float* cv = cvals + ((size_t)e << 4);
  const int* ti = topi + ((size_t)e << 4);
  float cc[16];
  int ix[16];
#pragma unroll
  for (int p = 0; p < 16; ++p) { cc[p] = cv[p]; ix[p] = ti[p]; }
  float4 acc[4] = {};
#pragma unroll
  for (int h = 0; h < 2; ++h) {
    float4 g[8];
#pragma unroll
    for (int p = 0; p < 8; ++p)
      g[p] = *(const float4*)(M + ((size_t)ix[h * 8 + p] << 8) + cb);
#pragma unroll
    for (int p = 0; p < 8; ++p) {
      float c = cc[h * 8 + p];
      float4 gg = g[p];
      int a = p & 3;
      acc[a].x += c * gg.x; acc[a].y += c * gg.y;
      acc[a].z += c * gg.z; acc[a].w += c * gg.w;
    }
  }
  float4 r;
  r.x = (acc[0].x + acc[1].x) + (acc[2].x + acc[3].x);
  r.y = (acc[0].y + acc[1].y) + (acc[2].y + acc[3].y);
  r.z = (acc[0].z + acc[1].z) + (acc[2].z + acc[3].z);
  r.w = (acc[0].w + acc[1].w) + (acc[2].w + acc[3].w);
  *(float4*)(G + ((size_t)e << 8) + cb) = r;
}

// Z = S_norm @ M via CSR rows + fused epilogues
template <int MODE>
__global__ __launch_bounds__(256) void spmm_row_ep(
    const int* __restrict__ rowptr, const int* __restrict__ colE,
    const float* __restrict__ cvalR, const float* __restrict__ G,
    const float* __restrict__ Xf, float* __restrict__ T1,
    const float* __restrict__ Zk, const float* __restrict__ thetaf,
    const float* __restrict__ scal, h16* __restrict__ Zmh,
    h16* __restrict__ Zml) {
  int wid = threadIdx.x >> 6, lane = threadIdx.x & 63;
  int row = blockIdx.x * 4 + wid;  // grid 1024
  int cb = lane << 2;
  int s = rowptr[row], e = rowptr[row + 1];
  float4 acc[4] = {};
  int j = s;
  for (; j + 8 <= e; j += 8) {
    int ix[8];
    float cc[8];
#pragma unroll
    for (int t = 0; t < 8; ++t) { ix[t] = colE[j + t]; cc[t] = cvalR[j + t]; }
    float4 g[8];
#pragma unroll
    for (int t = 0; t < 8; ++t)
      g[t] = *(const float4*)(G + ((size_t)ix[t] << 8) + cb);
#pragma unroll
    for (int t = 0; t < 8; ++t) {
      float c = cc[t];
      float4 gg = g[t];
      int a = t & 3;
      acc[a].x += c * gg.x; acc[a].y += c * gg.y;
      acc[a].z += c * gg.z; acc[a].w += c * gg.w;
    }
  }
  for (; j < e; ++j) {
    float c = cvalR[j];
    float4 gg = *(const float4*)(G + ((size_t)colE[j] << 8) + cb);
    acc[0].x += c * gg.x; acc[0].y += c * gg.y;
    acc[0].z += c * gg.z; acc[0].w += c * gg.w;
  }
  float4 z;
  z.x = (acc[0].x + acc[1].x) + (acc[2].x + acc[3].x);
  z.y = (acc[0].y + acc[1].y) + (acc[2].y + acc[3].y);
  z.z = (acc[0].z + acc[1].z) + (acc[2].z + acc[3].z);
  z.w = (acc[0].w + acc[1].w) + (acc[2].w + acc[3].w);
  size_t o = ((size_t)row << 8) + cb;
  float c1 = 2.0f / scal[5];
  float4 x = *(const float4*)(Xf + o);
  if constexpr (MODE == 1) {
    float4 t1;
    t1.x = (c1 - 1.0f) * x.x - c1 * z.x;
    t1.y = (c1 - 1.0f) * x.y - c1 * z.y;
    t1.z = (c1 - 1.0f) * x.z - c1 * z.z;
    t1.w = (c1 - 1.0f) * x.w - c1 * z.w;
    *(float4*)(T1 + o) = t1;
  } else {
    float rho = scal[4];
    float4 t1 = *(const float4*)(T1 + o);
    float4 zk = *(const float4*)(Zk + o);
    h16x4 hh, hl;
#pragma unroll
    for (int q = 0; q < 4; ++q) {
      float xv = (&x.x)[q], t1v = (&t1.x)[q], zv = (&z.x)[q], zkv = (&zk.x)[q];
      int d = cb + q;
      float t2 = 2.0f * ((c1 - 1.0f) * t1v - c1 * zv) - xv;
      float oo = xv * thetaf[d] + t1v * thetaf[256 + d] + t2 * thetaf[512 + d];
      float zs = oo > 0.0f ? oo : expm1f(oo);
      float zm = rho * zs + (1.0f - rho) * zkv;
      h16 h = (h16)zm;
      hh[q] = h;
      hl[q] = (h16)(zm - (float)h);
    }
    *(h16x4*)(Zmh + o) = hh;
    *(h16x4*)(Zml + o) = hl;
  }
}

// ---------------------------------------------------------------------------
extern "C" void kernel_launch(void* const* d_in, const int* in_sizes, int n_in,
                              void* d_out, int out_size, void* d_ws,
                              size_t ws_size, hipStream_t stream) {
  (void)in_sizes; (void)n_in; (void)out_size;
  const void* Xin = d_in[0];
  const void* Lin = d_in[1];
  const void* alpha = d_in[2];
  const void* theta = d_in[3];
  const void* rho_raw = d_in[4];
  const void* Wpin = d_in[5];
  const void* bpin = d_in[6];
  float* out = (float*)d_out;

  char* base = (char*)d_ws;
  size_t off = 0;
  auto alloc = [&](size_t bytes) -> char* {
    char* p = base + off;
    off += (bytes + 255) & ~(size_t)255;
    return p;
  };
  float* Abuf = (float*)alloc((size_t)4096 * 4096 * 4);   // A; 16 ks-partials; G
  h16* Eall = (h16*)alloc((size_t)4 * 4096 * 4096 * 2);   // 4 E planes
  h16* Yhi = (h16*)alloc((size_t)4 * 4096 * 256 * 2);
  h16* Ylo = (h16*)alloc((size_t)4 * 4096 * 256 * 2);
  h16* Xhi = (h16*)alloc((size_t)4096 * 256 * 2);
  h16* Xlo = (h16*)alloc((size_t)4096 * 256 * 2);
  float* Xf = (float*)alloc((size_t)4096 * 256 * 4);
  h16* XT = (h16*)alloc((size_t)256 * 4096 * 2);
  h16* Lhi = (h16*)alloc((size_t)4 * 256 * 256 * 2);
  h16* Llo = (h16*)alloc((size_t)4 * 256 * 256 * 2);   // contiguous after Lhi
  h16* LThi = (h16*)alloc((size_t)4 * 256 * 256 * 2);
  h16* LTlo = (h16*)alloc((size_t)4 * 256 * 256 * 2);  // contiguous after LThi
  h16* Whi = (h16*)alloc((size_t)256 * 256 * 2);
  h16* Wlo = (h16*)alloc((size_t)256 * 256 * 2);
  float* Zk = (float*)alloc((size_t)4096 * 256 * 4);
  float* T1 = (float*)alloc((size_t)4096 * 256 * 4);
  h16* Zmh = (h16*)alloc((size_t)4096 * 256 * 2);
  h16* Zml = (h16*)alloc((size_t)4096 * 256 * 2);
  float* topv = (float*)alloc((size_t)4 * 4096 * 16 * 4);
  int* topi = (int*)alloc((size_t)4 * 4096 * 16 * 4);
  float* cvals = (float*)alloc((size_t)262144 * 4);
  int* colE = (int*)alloc((size_t)262144 * 4);
  float* cvalR = (float*)alloc((size_t)262144 * 4);
  int* pCnt = (int*)alloc((size_t)64 * 4096 * 4);
  float* pDv = (float*)alloc((size_t)64 * 4096 * 4);
  int* blockBase = (int*)alloc((size_t)64 * 4096 * 4);
  int* rowptr = (int*)alloc(4097 * 4);
  int* cnt = (int*)alloc(4096 * 4);
  float* Dvis = (float*)alloc(4096 * 4);
  float* DeIS = (float*)alloc(16384 * 4);
  float* gE = (float*)alloc(16384 * 4);
  float* wA = (float*)alloc(4096 * 4);
  float* wB = (float*)alloc(4096 * 4);
  float* rowSinv = (float*)alloc((size_t)4 * 4096 * 4);
  float* thetaf = (float*)alloc(768 * 4);
  float* biasf = (float*)alloc(256 * 4);
  float* scal = (float*)alloc(256);
  if (off > ws_size) return;
  float* Kpart = Abuf;  // 64 MB: 16 partial planes; A dead by then
  float* G = Abuf;      // 16 MB alias; partials dead after ksred_hist

  split_input3<<<1024, 256, 0, stream>>>(Xin, Xhi, Xlo, Xf, 4096 * 256);
  split_LW<<<320, 256, 0, stream>>>(Xin, Lin, Lhi, Llo, Wpin, Whi, Wlo);
  prep_small<<<1, 1024, 0, stream>>>(Xin, theta, bpin, alpha, rho_raw, thetaf,
                                     biasf, scal);
  transpose16<<<dim3(128, 8, 1), 256, 0, stream>>>((const u16*)Xhi, (u16*)XT,
                                                   4096, 256);
  // both L planes (Lhi|Llo contiguous -> LThi|LTlo contiguous), z = 8
  transpose16<<<dim3(8, 8, 8), 256, 0, stream>>>((const u16*)Lhi, (u16*)LThi,
                                                 256, 256);
  // Y = X @ L_k (split fp16, fused), hi/lo written directly, batched z=4
  gemm3_nt<false, true><<<dim3(4, 64, 4), 256, 0, stream>>>(
      Xhi, Xlo, LThi, LTlo, nullptr, Yhi, Ylo, nullptr, 1.0f, 4096, 256, 256,
      0L, 256L * 256L, 4096L * 256L);
  for (int k = 0; k < 4; ++k) {
    gemm3_big<<<dim3(32, 32), 256, 0, stream>>>(
        Yhi + (size_t)k * 4096 * 256, Ylo + (size_t)k * 4096 * 256, Xhi, Xlo,
        Abuf, 0.0625f, 4096, 4096, 256);
    row_softmax_topk<<<1024, 256, 0, stream>>>(
        Abuf, topv, topi, Eall + (size_t)k * 4096 * 4096, rowSinv + k * 4096,
        k);
  }
  // all 4 heads' E @ X: M-tile 64 x N-tile 256, K-split 4/head,
  // 512-thread (8-wave) blocks, syncthreads-only 2-deep double buffer
  // (1024 blocks = 4/CU by LDS, 32 waves/CU)
  gemm_ks4<<<dim3(64, 16), 512, 0, stream>>>(Eall, XT, Kpart);
  // Zk reduce (blocks 0..1023) + histogram build (blocks 1024..1087)
  ksred_hist<<<1088, 256, 0, stream>>>(Kpart, scal, rowSinv, Zk, topv, topi,
                                       pCnt, pDv, DeIS);
  col_scan<<<16, 256, 0, stream>>>(pCnt, pDv, cnt, Dvis, blockBase, wA);
  scan_rowptr<<<1, 256, 0, stream>>>(cnt, rowptr);
  csr_fill3<<<64, 256, 0, stream>>>(topv, topi, Dvis, DeIS, rowptr, blockBase,
                                    cvals, colE, cvalR);
  // power iteration (regular launches — cooperative launch fails graph capture)
  for (int it = 0; it < 6; ++it) {
    const float* vi = (it & 1) ? wB : wA;
    float* vo = (it & 1) ? wA : wB;
    spmv_edge<<<64, 256, 0, stream>>>(cvals, topi, vi, gE);
    spmv_row<<<1024, 256, 0, stream>>>(rowptr, colE, cvalR, gE, vi, vo);
  }
  pi_dots<<<1, 256, 0, stream>>>(wB, wA, scal);
  // SnX -> T1 (fused) ; SnT1 -> cheb/elu/mix -> Zmh/Zml (fused)
  spmm_edge<<<4096, 256, 0, stream>>>(cvals, topi, Xf, G);
  spmm_row_ep<1><<<1024, 256, 0, stream>>>(rowptr, colE, cvalR, G, Xf, T1,
                                           nullptr, thetaf, scal, nullptr,
                                           nullptr);
  spmm_edge<<<4096, 256, 0, stream>>>(cvals, topi, T1, G);
  spmm_row_ep<2><<<1024, 256, 0, stream>>>(rowptr, colE, cvalR, G, Xf, T1, Zk,
                                           thetaf, scal, Zmh, Zml);
  // out = Zmix @ proj_w^T + proj_b (split fp16, f32 out)
  gemm3_nt<true, false><<<dim3(4, 64, 1), 256, 0, stream>>>(
      Zmh, Zml, Whi, Wlo, out, nullptr, nullptr, biasf, 1.0f, 4096, 256, 256,
      0L, 0L, 0L);
}

// Round 5
// 661.433 us; speedup vs baseline: 1.0483x; 1.0483x over previous
//
#include <hip/hip_runtime.h>

typedef unsigned short u16;
typedef unsigned long long u64;
typedef _Float16 h16;
typedef __attribute__((ext_vector_type(8))) _Float16 h16x8;
typedef __attribute__((ext_vector_type(4))) _Float16 h16x4;
typedef __attribute__((ext_vector_type(4))) float f32x4;

__device__ __forceinline__ float b2f(u16 u) {
  unsigned x = ((unsigned)u) << 16;
  return __uint_as_float(x);
}
__device__ __forceinline__ unsigned fkey(float f) {
  unsigned b = __float_as_uint(f);
  return (b & 0x80000000u) ? ~b : (b | 0x80000000u);
}
__device__ __forceinline__ float unfkey(unsigned u) {
  unsigned b = (u & 0x80000000u) ? (u ^ 0x80000000u) : ~u;
  return __uint_as_float(b);
}
__device__ __forceinline__ f32x4 mfma16(h16x8 a, h16x8 b, f32x4 c) {
  return __builtin_amdgcn_mfma_f32_16x16x32_f16(a, b, c, 0, 0, 0);
}
__device__ __forceinline__ void gl_lds16(const void* g, void* l) {
  __builtin_amdgcn_global_load_lds(
      (const __attribute__((address_space(1))) unsigned*)g,
      (__attribute__((address_space(3))) unsigned*)l, 16, 0, 0);
}
__device__ __forceinline__ u64 wave_max_u64(u64 k) {
#pragma unroll
  for (int off = 32; off; off >>= 1) {
    u64 o = __shfl_xor(k, off);
    if (o > k) k = o;
  }
  return k;
}
__device__ __forceinline__ float cvt_in(const void* p, int i, int f) {
  return f ? ((const float*)p)[i] : b2f(((const u16*)p)[i]);
}

// per-block dtype detection from X's first 8192 u16 slots (same sample set
// as the old detect_dtype kernel); returns 1 if inputs are f32 (expected)
__device__ __forceinline__ int detect_f32_local(const u16* __restrict__ X) {
  __shared__ int dcnt;
  if (threadIdx.x == 0) dcnt = 0;
  __syncthreads();
  int sane = 0;
  for (int j = threadIdx.x; j < 4096; j += blockDim.x) {
    u16 u = X[j * 2];
    int e = (u >> 7) & 0xff;
    if (u == 0 || (e >= 112 && e <= 142)) sane++;
  }
  atomicAdd(&dcnt, sane);
  __syncthreads();
  return (dcnt < 3072) ? 1 : 0;
}

// split X to hi/lo fp16 + f32 copy (local dtype detect)
__global__ __launch_bounds__(256) void split_input3(
    const void* __restrict__ in, h16* __restrict__ hi, h16* __restrict__ lo,
    float* __restrict__ f32out, int n) {
  int f = detect_f32_local((const u16*)in);
  int stride = gridDim.x * 256;
  for (int i = blockIdx.x * 256 + threadIdx.x; i < n; i += stride) {
    float x = cvt_in(in, i, f);
    h16 h = (h16)x;
    hi[i] = h;
    lo[i] = (h16)(x - (float)h);
    if (f32out) f32out[i] = x;
  }
}

// split L (blocks 0..255) and W (blocks 256..319); local detect from X
__global__ __launch_bounds__(256) void split_LW(
    const void* __restrict__ Xin, const void* __restrict__ Lin,
    h16* __restrict__ Lhi, h16* __restrict__ Llo, const void* __restrict__ Win,
    h16* __restrict__ Whi, h16* __restrict__ Wlo) {
  int f = detect_f32_local((const u16*)Xin);
  int tid = threadIdx.x;
  if (blockIdx.x < 256) {
#pragma unroll
    for (int j = 0; j < 4; ++j) {
      int i = blockIdx.x * 1024 + j * 256 + tid;
      float x = cvt_in(Lin, i, f);
      h16 h = (h16)x;
      Lhi[i] = h;
      Llo[i] = (h16)(x - (float)h);
    }
  } else {
    int b = blockIdx.x - 256;
#pragma unroll
    for (int j = 0; j < 4; ++j) {
      int i = b * 1024 + j * 256 + tid;
      float x = cvt_in(Win, i, f);
      h16 h = (h16)x;
      Whi[i] = h;
      Wlo[i] = (h16)(x - (float)h);
    }
  }
}

// theta+bias conv + scalars (local detect from X)
__global__ __launch_bounds__(1024) void prep_small(
    const void* __restrict__ Xin, const void* __restrict__ theta,
    const void* __restrict__ bpin, const void* __restrict__ alpha,
    const void* __restrict__ rho_raw, float* __restrict__ thetaf,
    float* __restrict__ biasf, float* __restrict__ scal) {
  int f = detect_f32_local((const u16*)Xin);
  int tid = threadIdx.x;
  if (tid < 768)
    thetaf[tid] = cvt_in(theta, tid, f);
  else if (tid < 1024)
    biasf[tid - 768] = cvt_in(bpin, tid - 768, f);
  if (tid == 0) {
    float a[4], e[4], m = -1e30f, s = 0.f;
    for (int i = 0; i < 4; ++i) {
      a[i] = cvt_in(alpha, i, f);
      m = fmaxf(m, a[i]);
    }
    for (int i = 0; i < 4; ++i) { e[i] = expf(a[i] - m); s += e[i]; }
    for (int i = 0; i < 4; ++i) scal[i] = e[i] / s;
    float rr = cvt_in(rho_raw, 0, f);
    scal[4] = 1.f / (1.f + expf(-rr));
  }
}

// ---------------------------------------------------------------------------
// Split-precision NT GEMM (64x64 tile): alpha*(Ah Bh^T + Ah Bl^T + Al Bh^T)
// SPLITOUT=1: write hi/lo fp16 planes (Y path); else f32 C (+bias).
// ---------------------------------------------------------------------------
template <bool BIAS, bool SPLITOUT>
__global__ __launch_bounds__(256) void gemm3_nt(
    const h16* __restrict__ Ah, const h16* __restrict__ Al,
    const h16* __restrict__ Bh, const h16* __restrict__ Bl,
    float* __restrict__ C, h16* __restrict__ Yh, h16* __restrict__ Yl,
    const float* __restrict__ bias, float alpha, int M, int Nc, int Kd,
    long batchA, long batchB, long batchC) {
  const h16* Abh = Ah + (size_t)blockIdx.z * batchA;
  const h16* Abl = Al + (size_t)blockIdx.z * batchA;
  const h16* Bbh = Bh + (size_t)blockIdx.z * batchB;
  const h16* Bbl = Bl + (size_t)blockIdx.z * batchB;
  int bn = blockIdx.x, bm = blockIdx.y;
  int tid = threadIdx.x;
  int wid = tid >> 6, lane = tid & 63;
  __shared__ h16 Ash[64 * 40], Asl[64 * 40], Bsh[64 * 40], Bsl[64 * 40];
  f32x4 acc00 = {}, acc01 = {}, acc10 = {}, acc11 = {};
  int lr = tid >> 2;
  int lc = (tid & 3) << 3;
  size_t aoff = (size_t)(bm * 64 + lr) * Kd + lc;
  size_t boff = (size_t)(bn * 64 + lr) * Kd + lc;
  int wm = (wid & 1) * 32, wn = (wid >> 1) * 32;
  int fr = lane & 15;
  int fc = (lane >> 4) << 3;
  for (int k0 = 0; k0 < Kd; k0 += 32) {
    uint4 avh = *(const uint4*)(Abh + aoff + k0);
    uint4 avl = *(const uint4*)(Abl + aoff + k0);
    uint4 bvh = *(const uint4*)(Bbh + boff + k0);
    uint4 bvl = *(const uint4*)(Bbl + boff + k0);
    __syncthreads();
    *(uint4*)(Ash + lr * 40 + lc) = avh;
    *(uint4*)(Asl + lr * 40 + lc) = avl;
    *(uint4*)(Bsh + lr * 40 + lc) = bvh;
    *(uint4*)(Bsl + lr * 40 + lc) = bvl;
    __syncthreads();
    h16x8 a0h = *(const h16x8*)(Ash + (wm + fr) * 40 + fc);
    h16x8 a1h = *(const h16x8*)(Ash + (wm + 16 + fr) * 40 + fc);
    h16x8 b0h = *(const h16x8*)(Bsh + (wn + fr) * 40 + fc);
    h16x8 b1h = *(const h16x8*)(Bsh + (wn + 16 + fr) * 40 + fc);
    h16x8 a0l = *(const h16x8*)(Asl + (wm + fr) * 40 + fc);
    h16x8 a1l = *(const h16x8*)(Asl + (wm + 16 + fr) * 40 + fc);
    h16x8 b0l = *(const h16x8*)(Bsl + (wn + fr) * 40 + fc);
    h16x8 b1l = *(const h16x8*)(Bsl + (wn + 16 + fr) * 40 + fc);
    acc00 = mfma16(a0h, b0h, acc00);
    acc01 = mfma16(a0h, b1h, acc01);
    acc10 = mfma16(a1h, b0h, acc10);
    acc11 = mfma16(a1h, b1h, acc11);
    acc00 = mfma16(a0h, b0l, acc00);
    acc01 = mfma16(a0h, b1l, acc01);
    acc10 = mfma16(a1h, b0l, acc10);
    acc11 = mfma16(a1h, b1l, acc11);
    acc00 = mfma16(a0l, b0h, acc00);
    acc01 = mfma16(a0l, b1h, acc01);
    acc10 = mfma16(a1l, b0h, acc10);
    acc11 = mfma16(a1l, b1h, acc11);
  }
  int crow = (lane >> 4) << 2;
  int ccol = lane & 15;
  f32x4 accs[2][2] = {{acc00, acc01}, {acc10, acc11}};
#pragma unroll
  for (int i = 0; i < 2; ++i)
#pragma unroll
    for (int j = 0; j < 2; ++j) {
      int r0 = bm * 64 + wm + 16 * i + crow;
      int c0 = bn * 64 + wn + 16 * j + ccol;
#pragma unroll
      for (int rg = 0; rg < 4; ++rg) {
        size_t off = (size_t)(r0 + rg) * Nc + c0;
        float v = accs[i][j][rg] * alpha;
        if constexpr (SPLITOUT) {
          h16* Yhb = Yh + (size_t)blockIdx.z * batchC;
          h16* Ylb = Yl + (size_t)blockIdx.z * batchC;
          h16 hh = (h16)v;
          Yhb[off] = hh;
          Ylb[off] = (h16)(v - (float)hh);
        } else {
          if constexpr (BIAS) v += bias[c0];
          float* Cb = C + (size_t)blockIdx.z * batchC;
          Cb[off] = v;
        }
      }
    }
}

// ---------------------------------------------------------------------------
// Split-precision NT GEMM, 128x128 tile, global_load_lds staging, XOR swizzle.
// ---------------------------------------------------------------------------
__global__ __launch_bounds__(256) void gemm3_big(
    const h16* __restrict__ Ah, const h16* __restrict__ Al,
    const h16* __restrict__ Bh, const h16* __restrict__ Bl,
    float* __restrict__ C, float alpha, int M, int Nc, int Kd) {
  __shared__ h16 sAh[128 * 32], sAl[128 * 32], sBh[128 * 32], sBl[128 * 32];
  int tid = threadIdx.x, wid = tid >> 6, lane = tid & 63;
  int bm = blockIdx.y, bn = blockIdx.x;
  int srow = 32 * wid + (lane >> 2);
  int scnk = lane & 3;
  int fr = lane & 15, fcc = lane >> 4;
  f32x4 acc[4][4] = {};
  const h16* gA[2] = {Ah, Al};
  const h16* gB[2] = {Bh, Bl};
  h16* sA[2] = {sAh, sAl};
  h16* sB[2] = {sBh, sBl};
  int wm = (wid & 1) * 64, wn = (wid >> 1) * 64;
  for (int k0 = 0; k0 < Kd; k0 += 32) {
    __syncthreads();
#pragma unroll
    for (int h = 0; h < 2; ++h) {
      int r = srow + 16 * h;
      int cs = scnk ^ ((r >> 1) & 3);
      size_t goffA = (size_t)(bm * 128 + r) * Kd + k0 + cs * 8;
      size_t goffB = (size_t)(bn * 128 + r) * Kd + k0 + cs * 8;
      int loff = (32 * wid + 16 * h) * 32;
#pragma unroll
      for (int p = 0; p < 2; ++p) {
        gl_lds16(gA[p] + goffA, sA[p] + loff);
        gl_lds16(gB[p] + goffB, sB[p] + loff);
      }
    }
    __syncthreads();
    h16x8 fa[2][4], fb[2][4];
#pragma unroll
    for (int i = 0; i < 4; ++i) {
      int ra = wm + 16 * i + fr;
      int ca = (fcc ^ ((ra >> 1) & 3)) * 8;
      fa[0][i] = *(const h16x8*)(sAh + ra * 32 + ca);
      fa[1][i] = *(const h16x8*)(sAl + ra * 32 + ca);
      int rb = wn + 16 * i + fr;
      int cb = (fcc ^ ((rb >> 1) & 3)) * 8;
      fb[0][i] = *(const h16x8*)(sBh + rb * 32 + cb);
      fb[1][i] = *(const h16x8*)(sBl + rb * 32 + cb);
    }
#pragma unroll
    for (int i = 0; i < 4; ++i)
#pragma unroll
      for (int j = 0; j < 4; ++j) {
        acc[i][j] = mfma16(fa[0][i], fb[0][j], acc[i][j]);
        acc[i][j] = mfma16(fa[0][i], fb[1][j], acc[i][j]);
        acc[i][j] = mfma16(fa[1][i], fb[0][j], acc[i][j]);
      }
  }
  int crow = (lane >> 4) << 2, ccol = lane & 15;
#pragma unroll
  for (int i = 0; i < 4; ++i)
#pragma unroll
    for (int j = 0; j < 4; ++j) {
      int r0 = bm * 128 + wm + 16 * i + crow;
      int c0 = bn * 128 + wn + 16 * j + ccol;
#pragma unroll
      for (int rg = 0; rg < 4; ++rg)
        C[(size_t)(r0 + rg) * Nc + c0] = acc[i][j][rg] * alpha;
    }
}

// ---------------------------------------------------------------------------
// fp16 NT GEMM for all 4 heads' E@X.
// v5: v3 tiling (M64 x N256, BK=32, 256 thr, 40 KB dbuf LDS, grid (64,16))
// but T14 reg-staging with 2-deep prefetch: plain global->reg loads survive
// __syncthreads() (only stores/LDS ops are drained), so each block keeps TWO
// K-tiles (40 KB) of global loads in flight at all times -> 8x deeper HBM
// request stream than v3's gl_lds+drain (which plateaued at 2.5 TB/s).
// Swizzle applied on ds_write AND ds_read (same XOR; both-sides rule).
// ---------------------------------------------------------------------------
__global__ __launch_bounds__(256) void gemm_ks4(
    const h16* __restrict__ Eall, const h16* __restrict__ B,
    float* __restrict__ Cpart) {
  __shared__ h16 sA[2][64 * 32];    // 8 KB
  __shared__ h16 sB[2][256 * 32];   // 32 KB
  int tid = threadIdx.x, wid = tid >> 6, lane = tid & 63;
  int bm = blockIdx.x, zz = blockIdx.y;  // grid (64, 16)
  int head = zz >> 2, kz = zz & 3;
  const h16* A =
      Eall + (size_t)head * 4096 * 4096 + (size_t)(bm * 64) * 4096 + kz * 1024;
  const h16* Bb = B + kz * 1024;
  int r16 = lane >> 2;   // 0..15 (row within a 16-row staging slab)
  int scnk = lane & 3;   // 16B chunk within 32-col row
  int fr = lane & 15, fcc = lane >> 4;
  int wn = wid * 64;     // wave's 64-col slice of the 256-wide N tile
  f32x4 acc[4][4] = {};

  // per-lane global element offsets (A: 1 row slab; B: 4 row slabs)
  int rA = 16 * wid + r16;
  size_t gA = (size_t)rA * 4096 + scnk * 8;
  size_t gB[4];
  int dB[4];
  int dA = rA * 32 + ((scnk ^ ((rA >> 1) & 3)) << 3);
#pragma unroll
  for (int p = 0; p < 4; ++p) {
    int rB = 64 * p + 16 * wid + r16;
    gB[p] = (size_t)rB * 4096 + scnk * 8;
    dB[p] = rB * 32 + ((scnk ^ ((rB >> 1) & 3)) << 3);
  }

  uint4 rgA, rgB0, rgB1, rgB2, rgB3;
  auto gload = [&](int k0) {
    rgA = *(const uint4*)(A + gA + k0);
    rgB0 = *(const uint4*)(Bb + gB[0] + k0);
    rgB1 = *(const uint4*)(Bb + gB[1] + k0);
    rgB2 = *(const uint4*)(Bb + gB[2] + k0);
    rgB3 = *(const uint4*)(Bb + gB[3] + k0);
  };
  auto swrite = [&](int buf) {
    *(uint4*)(&sA[buf][dA]) = rgA;
    *(uint4*)(&sB[buf][dB[0]]) = rgB0;
    *(uint4*)(&sB[buf][dB[1]]) = rgB1;
    *(uint4*)(&sB[buf][dB[2]]) = rgB2;
    *(uint4*)(&sB[buf][dB[3]]) = rgB3;
  };
  auto compute = [&](int buf) {
    h16x8 fa[4], fb[4];
#pragma unroll
    for (int i = 0; i < 4; ++i) {
      int ra = 16 * i + fr;
      int ca = (fcc ^ ((ra >> 1) & 3)) * 8;
      fa[i] = *(const h16x8*)(&sA[buf][ra * 32 + ca]);
      int rb = wn + 16 * i + fr;
      int cb = (fcc ^ ((rb >> 1) & 3)) * 8;
      fb[i] = *(const h16x8*)(&sB[buf][rb * 32 + cb]);
    }
#pragma unroll
    for (int i = 0; i < 4; ++i)
#pragma unroll
      for (int j = 0; j < 4; ++j)
        acc[i][j] = mfma16(fa[i], fb[j], acc[i][j]);
  };

  // prologue: tile0 -> buf0 (regs, waits its own vmcnt at swrite);
  // tile1 loads issued and left in flight across the barrier.
  gload(0);
  swrite(0);
  gload(32);
  __syncthreads();  // buf0 visible to all waves
  for (int t = 0; t < 32; ++t) {
    int cur = t & 1;
    if (t < 31) {
      swrite(cur ^ 1);             // regs hold tile t+1 (issued 1 iter ago)
      if (t < 30) gload((t + 2) * 32);  // tile t+2: flies across the barrier
    }
    compute(cur);
    __syncthreads();  // swrite(t+1) visible before compute(t+1)
  }

  float* Cp = Cpart + (size_t)zz * 4096 * 256;
  int crow = (lane >> 4) << 2, ccol = lane & 15;
#pragma unroll
  for (int i = 0; i < 4; ++i)
#pragma unroll
    for (int j = 0; j < 4; ++j) {
      int r0 = bm * 64 + 16 * i + crow;
      int c0 = wn + 16 * j + ccol;
#pragma unroll
      for (int rg = 0; rg < 4; ++rg)
        Cp[(size_t)(r0 + rg) * 256 + c0] = acc[i][j][rg];
    }
}

// merged: blocks 0..1023 = ks_reduce4 (Zk); blocks 1024..1087 = hist_part
__global__ __launch_bounds__(256) void ksred_hist(
    const float* __restrict__ Cpart, const float* __restrict__ scal,
    const float* __restrict__ rowSinv, float* __restrict__ Zk,
    const float* __restrict__ topv, const int* __restrict__ topi,
    int* __restrict__ pCnt, float* __restrict__ pDv,
    float* __restrict__ DeIS) {
  __shared__ int lc[4096];
  __shared__ float ld[4096];
  int tid = threadIdx.x;
  if (blockIdx.x < 1024) {
    int i = (blockIdx.x * 256 + tid) * 4;
    int row = i >> 8;
    float4 out = {0.f, 0.f, 0.f, 0.f};
#pragma unroll
    for (int k = 0; k < 4; ++k) {
      float4 s = {0.f, 0.f, 0.f, 0.f};
#pragma unroll
      for (int z = 0; z < 4; ++z) {
        float4 p =
            *(const float4*)(Cpart + (size_t)(k * 4 + z) * 4096 * 256 + i);
        s.x += p.x; s.y += p.y; s.z += p.z; s.w += p.w;
      }
      float sc = scal[k] * rowSinv[k * 4096 + row];
      out.x += sc * s.x; out.y += sc * s.y;
      out.z += sc * s.z; out.w += sc * s.w;
    }
    *(float4*)(Zk + i) = out;
  } else {
    int b = blockIdx.x - 1024;  // 0..63
    for (int j = tid; j < 4096; j += 256) { lc[j] = 0; ld[j] = 0.f; }
    __syncthreads();
    int base = b * 4096;
#pragma unroll
    for (int j = 0; j < 16; ++j) {
      int t = base + j * 256 + tid;
      atomicAdd(&lc[topi[t]], 1);
      atomicAdd(&ld[topi[t]], topv[t]);
    }
    __syncthreads();
    for (int j = tid; j < 4096; j += 256) {
      pCnt[base + j] = lc[j];
      pDv[base + j] = ld[j];
    }
    int e = b * 256 + tid;
    const float4* p = (const float4*)(topv + ((size_t)e << 4));
    float4 a = p[0], bb = p[1], c = p[2], d = p[3];
    float s = ((a.x + a.y) + (a.z + a.w)) + ((bb.x + bb.y) + (bb.z + bb.w)) +
              ((c.x + c.y) + (c.z + c.w)) + ((d.x + d.y) + (d.z + d.w));
    DeIS[e] = 1.0f / sqrtf(s + 1e-9f);
  }
}

// 16-bit transpose
__global__ __launch_bounds__(256) void transpose16(
    const u16* __restrict__ in, u16* __restrict__ out, int rows, int cols) {
  __shared__ u16 t[32][33];
  const u16* ib = in + (size_t)blockIdx.z * rows * cols;
  u16* ob = out + (size_t)blockIdx.z * rows * cols;
  int r0 = blockIdx.x * 32, c0 = blockIdx.y * 32;
  int tx = threadIdx.x & 31, ty = threadIdx.x >> 5;
#pragma unroll
  for (int i = 0; i < 32; i += 8)
    t[ty + i][tx] = ib[(size_t)(r0 + ty + i) * cols + c0 + tx];
  __syncthreads();
#pragma unroll
  for (int i = 0; i < 32; i += 8)
    ob[(size_t)(c0 + ty + i) * rows + r0 + tx] = t[tx][ty + i];
}

// ---------------------------------------------------------------------------
// fused per-row (one wave per row): max -> threshold T -> exp/E-write +
// candidate push -> exact jax-tiebreak top-16 from candidates
// ---------------------------------------------------------------------------
__global__ __launch_bounds__(256) void row_softmax_topk(
    const float* __restrict__ A, float* __restrict__ topv,
    int* __restrict__ topi, h16* __restrict__ E, float* __restrict__ rowSinvK,
    int khead) {
  __shared__ u64 candK[4][256];
  __shared__ int candN[4];
  int wid = threadIdx.x >> 6, lane = threadIdx.x & 63;
  int row = blockIdx.x * 4 + wid;
  const float* arow = A + ((size_t)row << 12);
  if (lane == 0) candN[wid] = 0;
  __syncthreads();
  float lm = -INFINITY;
#pragma unroll
  for (int t = 0; t < 16; ++t) {
    float4 v = *(const float4*)(arow + (t << 8) + (lane << 2));
    lm = fmaxf(lm, fmaxf(fmaxf(v.x, v.y), fmaxf(v.z, v.w)));
  }
  float m = lm;
#pragma unroll
  for (int off = 32; off; off >>= 1) m = fmaxf(m, __shfl_xor(m, off));
  u64 lk = ((u64)fkey(lm) << 32) | (unsigned)lane;
  float T = 0.f;
  for (int r = 0; r < 16; ++r) {
    u64 k2 = wave_max_u64(lk);
    if (lk == k2) lk = 0;
    if (r == 15) T = unfkey((unsigned)(k2 >> 32));
  }
  h16* erow = E + ((size_t)row << 12);
  int* cn = &candN[wid];
  u64* ck = candK[wid];
  float s = 0.f;
  for (int t = 0; t < 16; ++t) {
    int c = (t << 8) + (lane << 2);
    float4 v = *(const float4*)(arow + c);
    float e0 = __expf(v.x - m), e1 = __expf(v.y - m);
    float e2 = __expf(v.z - m), e3 = __expf(v.w - m);
    s += (e0 + e1) + (e2 + e3);
    h16x4 hv = {(h16)e0, (h16)e1, (h16)e2, (h16)e3};
    *(h16x4*)(erow + c) = hv;
    if (v.x >= T) {
      int sl = atomicAdd(cn, 1);
      if (sl < 256) ck[sl] = ((u64)fkey(v.x) << 32) | (unsigned)(~(unsigned)c);
    }
    if (v.y >= T) {
      int sl = atomicAdd(cn, 1);
      if (sl < 256) ck[sl] = ((u64)fkey(v.y) << 32) | (unsigned)(~(unsigned)(c + 1));
    }
    if (v.z >= T) {
      int sl = atomicAdd(cn, 1);
      if (sl < 256) ck[sl] = ((u64)fkey(v.z) << 32) | (unsigned)(~(unsigned)(c + 2));
    }
    if (v.w >= T) {
      int sl = atomicAdd(cn, 1);
      if (sl < 256) ck[sl] = ((u64)fkey(v.w) << 32) | (unsigned)(~(unsigned)(c + 3));
    }
  }
#pragma unroll
  for (int off = 32; off; off >>= 1) s += __shfl_xor(s, off);
  if (lane == 0) rowSinvK[row] = 1.f / s;
  __syncthreads();
  int cnt = min(*cn, 256);
  u64 loc[4] = {0ull, 0ull, 0ull, 0ull};
  int nl = 0;
  for (int j = lane; j < cnt; j += 64)
    if (nl < 4) loc[nl++] = ck[j];
#define CSW(a, b)                     \
  {                                   \
    if (loc[b] > loc[a]) {            \
      u64 tt = loc[a];                \
      loc[a] = loc[b];                \
      loc[b] = tt;                    \
    }                                 \
  }
  CSW(0, 1) CSW(2, 3) CSW(0, 2) CSW(1, 3) CSW(1, 2)
#undef CSW
  float myv = 0.f;
  int myi = 0;
  float sum16 = 0.f;
  for (int r = 0; r < 16; ++r) {
    u64 key = loc[0];
    u64 k2 = wave_max_u64(key);
    float wv = unfkey((unsigned)(k2 >> 32));
    int wi = (int)(~(unsigned)(k2 & 0xffffffffu));
    if (key == k2 && key != 0ull) {
      loc[0] = loc[1];
      loc[1] = loc[2];
      loc[2] = loc[3];
      loc[3] = 0ull;
    }
    sum16 += expf(wv - m);
    if (r == lane) { myv = wv; myi = wi; }
  }
  if (lane < 16) {
    size_t o = (((size_t)khead << 12) + row) * 16 + lane;
    topv[o] = expf(myv - m) / (sum16 + 1e-9f * s);
    topi[o] = myi;
  }
}

// per-bin reduce over 64 blocks: cnt, Dvis, block prefix; + fused v0 init
__global__ __launch_bounds__(256) void col_scan(
    const int* __restrict__ pCnt, const float* __restrict__ pDv,
    int* __restrict__ cnt, float* __restrict__ Dvis,
    int* __restrict__ blockBase, float* __restrict__ v0) {
  int i = blockIdx.x * 256 + threadIdx.x;  // grid 16 -> 4096
  int run = 0;
  float dv = 0.f;
#pragma unroll
  for (int b = 0; b < 64; ++b) {
    blockBase[b * 4096 + i] = run;
    run += pCnt[b * 4096 + i];
    dv += pDv[b * 4096 + i];
  }
  cnt[i] = run;
  Dvis[i] = sqrtf(1.0f / (dv + 1e-9f));
  {
    int tid = i;
    unsigned j = (unsigned)(tid & 2047);
    unsigned x0 = j, x1 = j + 2048u;
    const unsigned ks0 = 0u, ks1 = 1u, ks2 = 0x1BD11BDAu;
#define TF_R(r)                                \
    {                                          \
      x0 += x1;                                \
      x1 = (x1 << (r)) | (x1 >> (32 - (r)));   \
      x1 ^= x0;                                \
    }
    x0 += ks0; x1 += ks1;
    TF_R(13) TF_R(15) TF_R(26) TF_R(6)  x0 += ks1; x1 += ks2 + 1u;
    TF_R(17) TF_R(29) TF_R(16) TF_R(24) x0 += ks2; x1 += ks0 + 2u;
    TF_R(13) TF_R(15) TF_R(26) TF_R(6)  x0 += ks0; x1 += ks1 + 3u;
    TF_R(17) TF_R(29) TF_R(16) TF_R(24) x0 += ks1; x1 += ks2 + 4u;
    TF_R(13) TF_R(15) TF_R(26) TF_R(6)  x0 += ks2; x1 += ks0 + 5u;
#undef TF_R
    unsigned bits = (tid < 2048) ? x0 : x1;
    float u01 = __uint_as_float((bits >> 9) | 0x3f800000u) - 1.0f;
    const float lo = -0.99999994f;
    float u = fmaxf(lo, u01 * 2.0f + lo);
    float w = -log1pf(-u * u);
    float p;
    if (w < 5.0f) {
      float t = w - 2.5f;
      p = 2.81022636e-08f;
      p = 3.43273939e-07f + p * t;
      p = -3.5233877e-06f + p * t;
      p = -4.39150654e-06f + p * t;
      p = 0.00021858087f + p * t;
      p = -0.00125372503f + p * t;
      p = -0.00417768164f + p * t;
      p = 0.246640727f + p * t;
      p = 1.50140941f + p * t;
    } else {
      float t = sqrtf(w) - 3.0f;
      p = -0.000200214257f;
      p = 0.000100950558f + p * t;
      p = 0.00134934322f + p * t;
      p = -0.00367342844f + p * t;
      p = 0.00573950773f + p * t;
      p = -0.0076224613f + p * t;
      p = 0.00943887047f + p * t;
      p = 1.00167406f + p * t;
      p = 2.83297682f + p * t;
    }
    v0[tid] = 1.41421354f * (p * u);
  }
}

// exclusive scan of cnt[4096] -> rowptr[4097]
__global__ __launch_bounds__(256) void scan_rowptr(const int* __restrict__ cnt,
                                                   int* __restrict__ rowptr) {
  __shared__ int part[256];
  int tid = threadIdx.x;
  int base = tid * 16;
  int loc[16];
  int s = 0;
#pragma unroll
  for (int j = 0; j < 16; ++j) { loc[j] = s; s += cnt[base + j]; }
  part[tid] = s;
  __syncthreads();
  for (int off = 1; off < 256; off <<= 1) {
    int v = (tid >= off) ? part[tid - off] : 0;
    __syncthreads();
    part[tid] += v;
    __syncthreads();
  }
  int pre = (tid == 0) ? 0 : part[tid - 1];
#pragma unroll
  for (int j = 0; j < 16; ++j) rowptr[base + j] = pre + loc[j];
  if (tid == 255) rowptr[4096] = part[255];
}

// fill cvals + CSR transpose via LDS cursors (no global atomics)
__global__ __launch_bounds__(256) void csr_fill3(
    const float* __restrict__ topv, const int* __restrict__ topi,
    const float* __restrict__ Dvis, const float* __restrict__ DeIS,
    const int* __restrict__ rowptr, const int* __restrict__ blockBase,
    float* __restrict__ cvals, int* __restrict__ colE,
    float* __restrict__ cvalR) {
  __shared__ int lcur[4096];
  int tid = threadIdx.x, b = blockIdx.x;  // grid 64
  int base = b * 4096;
  for (int j = tid; j < 4096; j += 256)
    lcur[j] = rowptr[j] + blockBase[base + j];
  __syncthreads();
#pragma unroll
  for (int j = 0; j < 16; ++j) {
    int t = base + j * 256 + tid;
    int i = topi[t];
    int e = t >> 4;
    float c = Dvis[i] * topv[t] * DeIS[e];
    cvals[t] = c;
    int slot = atomicAdd(&lcur[i], 1);
    colE[slot] = e;
    cvalR[slot] = c;
  }
}

// g[e] = sum_p c[e,p] * v[idx[e,p]]
__global__ __launch_bounds__(256) void spmv_edge(
    const float* __restrict__ cvals, const int* __restrict__ topi,
    const float* __restrict__ v, float* __restrict__ g) {
  int e = blockIdx.x * 256 + threadIdx.x;  // grid 64
  float acc = 0.f;
#pragma unroll
  for (int p = 0; p < 16; ++p)
    acc += cvals[e * 16 + p] * v[topi[e * 16 + p]];
  g[e] = acc;
}

// vout[i] = vin[i] - sum_{j in row i} cvalR[j]*g[colE[j]]
__global__ __launch_bounds__(256) void spmv_row(
    const int* __restrict__ rowptr, const int* __restrict__ colE,
    const float* __restrict__ cvalR, const float* __restrict__ g,
    const float* __restrict__ vin, float* __restrict__ vout) {
  int wid = threadIdx.x >> 6, lane = threadIdx.x & 63;
  int row = blockIdx.x * 4 + wid;  // grid 1024
  int s = rowptr[row], e = rowptr[row + 1];
  float acc = 0.f;
  for (int j = s + lane; j < e; j += 64) acc += cvalR[j] * g[colE[j]];
#pragma unroll
  for (int off = 32; off; off >>= 1) acc += __shfl_xor(acc, off);
  if (lane == 0) vout[row] = vin[row] - acc;
}

// lam = clip((w5.w6)/(w5.w5), 1e-3) -> scal[5]
__global__ __launch_bounds__(256) void pi_dots(const float* __restrict__ w5,
                                               const float* __restrict__ w6,
                                               float* __restrict__ scal) {
  __shared__ float r1[256], r2[256];
  int tid = threadIdx.x;
  float a = 0.f, b = 0.f;
  for (int i = tid; i < 4096; i += 256) {
    float x = w5[i];
    a += x * x;
    b += x * w6[i];
  }
  r1[tid] = a; r2[tid] = b;
  __syncthreads();
  for (int off = 128; off; off >>= 1) {
    if (tid < off) { r1[tid] += r1[tid + off]; r2[tid] += r2[tid + off]; }
    __syncthreads();
  }
  if (tid == 0) scal[5] = fmaxf(r2[0] / r1[0], 1e-3f);
}

// G[e,:] = sum_p c[e,p] * M[idx[e,p],:]  — MLP-unrolled
__global__ __launch_bounds__(256) void spmm_edge(
    const float* __restrict__ cvals, const int* __restrict__ topi,
    const float* __restrict__ M, float* __restrict__ G) {
  int wid = threadIdx.x >> 6, lane = threadIdx.x & 63;
  int e = blockIdx.x * 4 + wid;  // grid 4096
  int cb = lane << 2;
  const float* cv = cvals + ((size_t)e << 4);
  const int* ti = topi + ((size_t)e << 4);
  float cc[16];
  int ix[16];
#pragma unroll
  for (int p = 0; p < 16; ++p) { cc[p] = cv[p]; ix[p] = ti[p]; }
  float4 acc[4] = {};
#pragma unroll
  for (int h = 0; h < 2; ++h) {
    float4 g[8];
#pragma unroll
    for (int p = 0; p < 8; ++p)
      g[p] = *(const float4*)(M + ((size_t)ix[h * 8 + p] << 8) + cb);
#pragma unroll
    for (int p = 0; p < 8; ++p) {
      float c = cc[h * 8 + p];
      float4 gg = g[p];
      int a = p & 3;
      acc[a].x += c * gg.x; acc[a].y += c * gg.y;
      acc[a].z += c * gg.z; acc[a].w += c * gg.w;
    }
  }
  float4 r;
  r.x = (acc[0].x + acc[1].x) + (acc[2].x + acc[3].x);
  r.y = (acc[0].y + acc[1].y) + (acc[2].y + acc[3].y);
  r.z = (acc[0].z + acc[1].z) + (acc[2].z + acc[3].z);
  r.w = (acc[0].w + acc[1].w) + (acc[2].w + acc[3].w);
  *(float4*)(G + ((size_t)e << 8) + cb) = r;
}

// Z = S_norm @ M via CSR rows + fused epilogues
template <int MODE>
__global__ __launch_bounds__(256) void spmm_row_ep(
    const int* __restrict__ rowptr, const int* __restrict__ colE,
    const float* __restrict__ cvalR, const float* __restrict__ G,
    const float* __restrict__ Xf, float* __restrict__ T1,
    const float* __restrict__ Zk, const float* __restrict__ thetaf,
    const float* __restrict__ scal, h16* __restrict__ Zmh,
    h16* __restrict__ Zml) {
  int wid = threadIdx.x >> 6, lane = threadIdx.x & 63;
  int row = blockIdx.x * 4 + wid;  // grid 1024
  int cb = lane << 2;
  int s = rowptr[row], e = rowptr[row + 1];
  float4 acc[4] = {};
  int j = s;
  for (; j + 8 <= e; j += 8) {
    int ix[8];
    float cc[8];
#pragma unroll
    for (int t = 0; t < 8; ++t) { ix[t] = colE[j + t]; cc[t] = cvalR[j + t]; }
    float4 g[8];
#pragma unroll
    for (int t = 0; t < 8; ++t)
      g[t] = *(const float4*)(G + ((size_t)ix[t] << 8) + cb);
#pragma unroll
    for (int t = 0; t < 8; ++t) {
      float c = cc[t];
      float4 gg = g[t];
      int a = t & 3;
      acc[a].x += c * gg.x; acc[a].y += c * gg.y;
      acc[a].z += c * gg.z; acc[a].w += c * gg.w;
    }
  }
  for (; j < e; ++j) {
    float c = cvalR[j];
    float4 gg = *(const float4*)(G + ((size_t)colE[j] << 8) + cb);
    acc[0].x += c * gg.x; acc[0].y += c * gg.y;
    acc[0].z += c * gg.z; acc[0].w += c * gg.w;
  }
  float4 z;
  z.x = (acc[0].x + acc[1].x) + (acc[2].x + acc[3].x);
  z.y = (acc[0].y + acc[1].y) + (acc[2].y + acc[3].y);
  z.z = (acc[0].z + acc[1].z) + (acc[2].z + acc[3].z);
  z.w = (acc[0].w + acc[1].w) + (acc[2].w + acc[3].w);
  size_t o = ((size_t)row << 8) + cb;
  float c1 = 2.0f / scal[5];
  float4 x = *(const float4*)(Xf + o);
  if constexpr (MODE == 1) {
    float4 t1;
    t1.x = (c1 - 1.0f) * x.x - c1 * z.x;
    t1.y = (c1 - 1.0f) * x.y - c1 * z.y;
    t1.z = (c1 - 1.0f) * x.z - c1 * z.z;
    t1.w = (c1 - 1.0f) * x.w - c1 * z.w;
    *(float4*)(T1 + o) = t1;
  } else {
    float rho = scal[4];
    float4 t1 = *(const float4*)(T1 + o);
    float4 zk = *(const float4*)(Zk + o);
    h16x4 hh, hl;
#pragma unroll
    for (int q = 0; q < 4; ++q) {
      float xv = (&x.x)[q], t1v = (&t1.x)[q], zv = (&z.x)[q], zkv = (&zk.x)[q];
      int d = cb + q;
      float t2 = 2.0f * ((c1 - 1.0f) * t1v - c1 * zv) - xv;
      float oo = xv * thetaf[d] + t1v * thetaf[256 + d] + t2 * thetaf[512 + d];
      float zs = oo > 0.0f ? oo : expm1f(oo);
      float zm = rho * zs + (1.0f - rho) * zkv;
      h16 h = (h16)zm;
      hh[q] = h;
      hl[q] = (h16)(zm - (float)h);
    }
    *(h16x4*)(Zmh + o) = hh;
    *(h16x4*)(Zml + o) = hl;
  }
}

// ---------------------------------------------------------------------------
extern "C" void kernel_launch(void* const* d_in, const int* in_sizes, int n_in,
                              void* d_out, int out_size, void* d_ws,
                              size_t ws_size, hipStream_t stream) {
  (void)in_sizes; (void)n_in; (void)out_size;
  const void* Xin = d_in[0];
  const void* Lin = d_in[1];
  const void* alpha = d_in[2];
  const void* theta = d_in[3];
  const void* rho_raw = d_in[4];
  const void* Wpin = d_in[5];
  const void* bpin = d_in[6];
  float* out = (float*)d_out;

  char* base = (char*)d_ws;
  size_t off = 0;
  auto alloc = [&](size_t bytes) -> char* {
    char* p = base + off;
    off += (bytes + 255) & ~(size_t)255;
    return p;
  };
  float* Abuf = (float*)alloc((size_t)4096 * 4096 * 4);   // A; 16 ks-partials; G
  h16* Eall = (h16*)alloc((size_t)4 * 4096 * 4096 * 2);   // 4 E planes
  h16* Yhi = (h16*)alloc((size_t)4 * 4096 * 256 * 2);
  h16* Ylo = (h16*)alloc((size_t)4 * 4096 * 256 * 2);
  h16* Xhi = (h16*)alloc((size_t)4096 * 256 * 2);
  h16* Xlo = (h16*)alloc((size_t)4096 * 256 * 2);
  float* Xf = (float*)alloc((size_t)4096 * 256 * 4);
  h16* XT = (h16*)alloc((size_t)256 * 4096 * 2);
  h16* Lhi = (h16*)alloc((size_t)4 * 256 * 256 * 2);
  h16* Llo = (h16*)alloc((size_t)4 * 256 * 256 * 2);   // contiguous after Lhi
  h16* LThi = (h16*)alloc((size_t)4 * 256 * 256 * 2);
  h16* LTlo = (h16*)alloc((size_t)4 * 256 * 256 * 2);  // contiguous after LThi
  h16* Whi = (h16*)alloc((size_t)256 * 256 * 2);
  h16* Wlo = (h16*)alloc((size_t)256 * 256 * 2);
  float* Zk = (float*)alloc((size_t)4096 * 256 * 4);
  float* T1 = (float*)alloc((size_t)4096 * 256 * 4);
  h16* Zmh = (h16*)alloc((size_t)4096 * 256 * 2);
  h16* Zml = (h16*)alloc((size_t)4096 * 256 * 2);
  float* topv = (float*)alloc((size_t)4 * 4096 * 16 * 4);
  int* topi = (int*)alloc((size_t)4 * 4096 * 16 * 4);
  float* cvals = (float*)alloc((size_t)262144 * 4);
  int* colE = (int*)alloc((size_t)262144 * 4);
  float* cvalR = (float*)alloc((size_t)262144 * 4);
  int* pCnt = (int*)alloc((size_t)64 * 4096 * 4);
  float* pDv = (float*)alloc((size_t)64 * 4096 * 4);
  int* blockBase = (int*)alloc((size_t)64 * 4096 * 4);
  int* rowptr = (int*)alloc(4097 * 4);
  int* cnt = (int*)alloc(4096 * 4);
  float* Dvis = (float*)alloc(4096 * 4);
  float* DeIS = (float*)alloc(16384 * 4);
  float* gE = (float*)alloc(16384 * 4);
  float* wA = (float*)alloc(4096 * 4);
  float* wB = (float*)alloc(4096 * 4);
  float* rowSinv = (float*)alloc((size_t)4 * 4096 * 4);
  float* thetaf = (float*)alloc(768 * 4);
  float* biasf = (float*)alloc(256 * 4);
  float* scal = (float*)alloc(256);
  if (off > ws_size) return;
  float* Kpart = Abuf;  // 64 MB: 16 partial planes; A dead by then
  float* G = Abuf;      // 16 MB alias; partials dead after ksred_hist

  split_input3<<<1024, 256, 0, stream>>>(Xin, Xhi, Xlo, Xf, 4096 * 256);
  split_LW<<<320, 256, 0, stream>>>(Xin, Lin, Lhi, Llo, Wpin, Whi, Wlo);
  prep_small<<<1, 1024, 0, stream>>>(Xin, theta, bpin, alpha, rho_raw, thetaf,
                                     biasf, scal);
  transpose16<<<dim3(128, 8, 1), 256, 0, stream>>>((const u16*)Xhi, (u16*)XT,
                                                   4096, 256);
  // both L planes (Lhi|Llo contiguous -> LThi|LTlo contiguous), z = 8
  transpose16<<<dim3(8, 8, 8), 256, 0, stream>>>((const u16*)Lhi, (u16*)LThi,
                                                 256, 256);
  // Y = X @ L_k (split fp16, fused), hi/lo written directly, batched z=4
  gemm3_nt<false, true><<<dim3(4, 64, 4), 256, 0, stream>>>(
      Xhi, Xlo, LThi, LTlo, nullptr, Yhi, Ylo, nullptr, 1.0f, 4096, 256, 256,
      0L, 256L * 256L, 4096L * 256L);
  for (int k = 0; k < 4; ++k) {
    gemm3_big<<<dim3(32, 32), 256, 0, stream>>>(
        Yhi + (size_t)k * 4096 * 256, Ylo + (size_t)k * 4096 * 256, Xhi, Xlo,
        Abuf, 0.0625f, 4096, 4096, 256);
    row_softmax_topk<<<1024, 256, 0, stream>>>(
        Abuf, topv, topi, Eall + (size_t)k * 4096 * 4096, rowSinv + k * 4096,
        k);
  }
  // all 4 heads' E @ X: M-tile 64 x N-tile 256, K-split 4/head,
  // T14 reg-staged 2-deep prefetch, syncthreads-only (1024 blocks, 40 KB LDS)
  gemm_ks4<<<dim3(64, 16), 256, 0, stream>>>(Eall, XT, Kpart);
  // Zk reduce (blocks 0..1023) + histogram build (blocks 1024..1087)
  ksred_hist<<<1088, 256, 0, stream>>>(Kpart, scal, rowSinv, Zk, topv, topi,
                                       pCnt, pDv, DeIS);
  col_scan<<<16, 256, 0, stream>>>(pCnt, pDv, cnt, Dvis, blockBase, wA);
  scan_rowptr<<<1, 256, 0, stream>>>(cnt, rowptr);
  csr_fill3<<<64, 256, 0, stream>>>(topv, topi, Dvis, DeIS, rowptr, blockBase,
                                    cvals, colE, cvalR);
  // power iteration (regular launches — cooperative launch fails graph capture)
  for (int it = 0; it < 6; ++it) {
    const float* vi = (it & 1) ? wB : wA;
    float* vo = (it & 1) ? wA : wB;
    spmv_edge<<<64, 256, 0, stream>>>(cvals, topi, vi, gE);
    spmv_row<<<1024, 256, 0, stream>>>(rowptr, colE, cvalR, gE, vi, vo);
  }
  pi_dots<<<1, 256, 0, stream>>>(wB, wA, scal);
  // SnX -> T1 (fused) ; SnT1 -> cheb/elu/mix -> Zmh/Zml (fused)
  spmm_edge<<<4096, 256, 0, stream>>>(cvals, topi, Xf, G);
  spmm_row_ep<1><<<1024, 256, 0, stream>>>(rowptr, colE, cvalR, G, Xf, T1,
                                           nullptr, thetaf, scal, nullptr,
                                           nullptr);
  spmm_edge<<<4096, 256, 0, stream>>>(cvals, topi, T1, G);
  spmm_row_ep<2><<<1024, 256, 0, stream>>>(rowptr, colE, cvalR, G, Xf, T1, Zk,
                                           thetaf, scal, Zmh, Zml);
  // out = Zmix @ proj_w^T + proj_b (split fp16, f32 out)
  gemm3_nt<true, false><<<dim3(4, 64, 1), 256, 0, stream>>>(
      Zmh, Zml, Whi, Wlo, out, nullptr, nullptr, biasf, 1.0f, 4096, 256, 256,
      0L, 0L, 0L);
}